// Round 6
// baseline (322.776 us; speedup 1.0000x reference)
//
#include <hip/hip_runtime.h>

#define TT    524288
#define CHUNK 512
#define NCH   (TT / CHUNK)     // 1024 chunks
#define SUB   64               // subtile rows
#define NSUB  (CHUNK / SUB)    // 8

typedef __attribute__((ext_vector_type(8))) short short8;
typedef __attribute__((ext_vector_type(4))) float f32x4;

__device__ __forceinline__ unsigned short f2bf(float f) {
    union { float f; unsigned u; } v; v.f = f;
    unsigned r = v.u + 0x7FFFu + ((v.u >> 16) & 1u);   // RTNE
    return (unsigned short)(r >> 16);
}
// pack (a,b) -> bf16(a) | bf16(b)<<16
__device__ __forceinline__ unsigned packbf2(float a, float b) {
    union { float f; unsigned u; } va, vb; va.f = a; vb.f = b;
    unsigned ra = va.u + 0x7FFFu + ((va.u >> 16) & 1u);
    unsigned rb = vb.u + 0x7FFFu + ((vb.u >> 16) & 1u);
    return (ra >> 16) | (rb & 0xFFFF0000u);
}
__device__ __forceinline__ float2 unpackbf2(unsigned w) {
    union { unsigned u; float f; } a, b;
    a.u = w << 16; b.u = w & 0xFFFF0000u;
    return make_float2(a.f, b.f);
}
__device__ __forceinline__ float sigf(float v) {
    return __builtin_amdgcn_rcpf(1.0f + __expf(-v));   // v_exp + v_rcp
}

union U8 { uint4 u4; short8 s8; };

// ============================================================================
// prep: one-time W1/W2 f32 -> bf16 transposed layouts in workspace.
// w1bf[n*64+k] (128x64), w2bf[n*64+k] (32x64). Same RTNE as before.
// ============================================================================
__global__ void prep(const float* __restrict__ W1, const float* __restrict__ W2,
                     short* __restrict__ w1bf, short* __restrict__ w2bf)
{
    const int tid = threadIdx.x;
    for (int i = tid; i < 2048; i += 256) {
        float4 w4 = ((const float4*)W1)[i];
        int k = i >> 5, n0 = (i & 31) * 4;
        w1bf[(n0 + 0) * 64 + k] = (short)f2bf(w4.x);
        w1bf[(n0 + 1) * 64 + k] = (short)f2bf(w4.y);
        w1bf[(n0 + 2) * 64 + k] = (short)f2bf(w4.z);
        w1bf[(n0 + 3) * 64 + k] = (short)f2bf(w4.w);
    }
    for (int i = tid; i < 512; i += 256) {
        float4 w4 = ((const float4*)W2)[i];
        int k = i >> 3, n0 = (i & 7) * 4;
        w2bf[(n0 + 0) * 64 + k] = (short)f2bf(w4.x);
        w2bf[(n0 + 1) * 64 + k] = (short)f2bf(w4.y);
        w2bf[(n0 + 2) * 64 + k] = (short)f2bf(w4.z);
        w2bf[(n0 + 3) * 64 + k] = (short)f2bf(w4.w);
    }
}

// ============================================================================
// Phase A v5: NO W1 LDS staging — B-fragments read directly from w1bf
// (16 KB, L1/L2-resident) as short8. LDS = seg only (16.9 KB) -> occupancy
// now VGPR-limited (~24 waves/CU, ~2x v4). Zero barriers before the final
// fold. Same math/order as v4 -> bit-identical output.
// ============================================================================
__global__ __launch_bounds__(256, 3)
void aphase(const float* __restrict__ x, const short* __restrict__ w1bf,
            const float* __restrict__ B1,
            float* __restrict__ Aout, float* __restrict__ Bout,
            uint4* __restrict__ abg)
{
    __shared__ float segA[32 * 66], segB[32 * 66];  // band maps 16.9KB

    const int tid  = threadIdx.x;
    const int c    = blockIdx.x;
    const int wave = tid >> 6;
    const int lane = tid & 63;
    const int quad = lane >> 4;
    const int lr   = lane & 15;

    // bias per lane (L2-cached scalar-ish loads)
    float bb[8];
    #pragma unroll
    for (int j = 0; j < 8; ++j) bb[j] = B1[j * 16 + lr];

    const float* xbase = x + (size_t)c * CHUNK * 64;

    // fragment load address for (subtile ss, row-tile rt): 4x float4 per lane
    #define FRAGP(ss, rt) ((const float4*)(xbase + (size_t)(((ss) * 64 + (rt) * 16 + lr)) * 64) + quad * 2)

    // prologue: load fi=0
    const float4* p0 = FRAGP(wave, 0);
    float4 c0 = p0[0], c1 = p0[1], c2 = p0[8], c3 = p0[9];

    const bool h1 = (quad & 1) != 0;   // hi half of the quad pair
    const bool h2 = (quad & 2) != 0;   // hi half of the 16-row block

    for (int fi = 0; fi < 8; ++fi) {
        const int ss = (fi < 4) ? wave : (wave + 4);
        const int rt = fi & 3;

        // ---- convert current 16-row tile to bf16 A-frags (frees c0..c3) ----
        U8 ua, ub;
        ua.u4 = make_uint4(packbf2(c0.x, c0.y), packbf2(c0.z, c0.w),
                           packbf2(c1.x, c1.y), packbf2(c1.z, c1.w));
        ub.u4 = make_uint4(packbf2(c2.x, c2.y), packbf2(c2.z, c2.w),
                           packbf2(c3.x, c3.y), packbf2(c3.z, c3.w));
        const short8 a0 = ua.s8, a1 = ub.s8;

        // ---- immediately reload NEXT tile into c* (full-body latency window) ----
        if (fi < 7) {
            const int ns = (fi + 1 < 4) ? wave : (wave + 4);
            const int nr = (fi + 1) & 3;
            const float4* np = FRAGP(ns, nr);
            c0 = np[0]; c1 = np[1]; c2 = np[8]; c3 = np[9];
        }

        // ---- MFMA 16 rows x 128 cols; B-frags straight from global (L1-hot) ----
        f32x4 acc[8];
        #pragma unroll
        for (int j = 0; j < 8; ++j) {
            acc[j][0] = bb[j]; acc[j][1] = bb[j]; acc[j][2] = bb[j]; acc[j][3] = bb[j];
        }
        #pragma unroll
        for (int j = 0; j < 8; ++j) {
            const short8 b0 = *(const short8*)&w1bf[(j * 16 + lr) * 64 + quad * 8];
            const short8 b1 = *(const short8*)&w1bf[(j * 16 + lr) * 64 + quad * 8 + 32];
            acc[j] = __builtin_amdgcn_mfma_f32_16x16x32_bf16(a0, b0, acc[j], 0, 0, 0);
            acc[j] = __builtin_amdgcn_mfma_f32_16x16x32_bf16(a1, b1, acc[j], 0, 0, 0);
        }

        // ---- sigmoid; a=l*r, b=1-l; pack ----
        unsigned pk[4][4];
        #pragma unroll
        for (int j = 0; j < 4; ++j) {
            #pragma unroll
            for (int r = 0; r < 4; ++r) {
                float hl = sigf(acc[j][r]);
                float hr = sigf(acc[j + 4][r]);
                pk[j][r] = packbf2(hl * hr, 1.0f - hl);
            }
        }

        // ---- export ab directly from registers ----
        {
            uint4* dstq = abg + ((size_t)((c * NSUB + ss) * 16 + rt * 4 + quad)) * 64 + lr;
            #pragma unroll
            for (int j = 0; j < 4; ++j)
                dstq[j * 16] = make_uint4(pk[j][0], pk[j][1], pk[j][2], pk[j][3]);
        }

        // ---- band map fully in registers ----
        float Aa[4], Ba[4];
        #pragma unroll
        for (int j = 0; j < 4; ++j) {
            float A = 1.0f, Bv = 0.0f;
            #pragma unroll
            for (int r = 0; r < 4; ++r) {
                float2 f = unpackbf2(pk[j][r]);
                Bv = fmaf(f.x, Bv, f.y); A *= f.x;
            }
            Aa[j] = A; Ba[j] = Bv;
        }
        // ordered tree over quads: combine(hi,lo): A=A_hi*A_lo; B=fmaf(A_hi,B_lo,B_hi)
        #pragma unroll
        for (int j = 0; j < 4; ++j) {
            float Ap = __shfl_xor(Aa[j], 16);
            float Bp = __shfl_xor(Ba[j], 16);
            float Ahi = h1 ? Aa[j] : Ap;
            float Blo = h1 ? Bp    : Ba[j];
            float Bhi = h1 ? Ba[j] : Bp;
            Aa[j] *= Ap;
            Ba[j] = fmaf(Ahi, Blo, Bhi);

            Ap = __shfl_xor(Aa[j], 32);
            Bp = __shfl_xor(Ba[j], 32);
            Ahi = h2 ? Aa[j] : Ap;
            Blo = h2 ? Bp    : Ba[j];
            Bhi = h2 ? Ba[j] : Bp;
            Aa[j] *= Ap;
            Ba[j] = fmaf(Ahi, Blo, Bhi);
        }
        const float Asel = (quad == 0) ? Aa[0] : (quad == 1) ? Aa[1]
                         : (quad == 2) ? Aa[2] : Aa[3];
        const float Bsel = (quad == 0) ? Ba[0] : (quad == 1) ? Ba[1]
                         : (quad == 2) ? Ba[2] : Ba[3];
        const int band = ss * 4 + rt;
        segA[band * 66 + lane] = Asel;
        segB[band * 66 + lane] = Bsel;
    }
    #undef FRAGP

    __syncthreads();   // the only barrier
    if (tid < 64) {
        float sA = 1.0f, sB = 0.0f;
        for (int b = 0; b < 32; ++b) {
            float A2 = segA[b * 66 + tid], B2v = segB[b * 66 + tid];
            sB = fmaf(A2, sB, B2v); sA *= A2;
        }
        Aout[c * 64 + tid] = sA; Bout[c * 64 + tid] = sB;
    }
}

// ============================================================================
// Carry scan across 1024 chunk maps: 16 parallel segments of 64 (1024 thr).
// ============================================================================
__global__ void carry_scan(const float* __restrict__ Aar, const float* __restrict__ Bar,
                           float* __restrict__ carry)
{
    __shared__ float sA[16 * 66], sB[16 * 66];
    const int tid = threadIdx.x;
    const int ch = tid & 63, seg = tid >> 6;       // 16 segments
    const int c0 = seg * (NCH / 16);

    float A = 1.0f, B = 0.0f;
    #pragma unroll 8
    for (int i = 0; i < NCH / 16; ++i) {
        const int idx = c0 + i;
        const float a = Aar[idx * 64 + ch];
        const float b = Bar[idx * 64 + ch];
        B = fmaf(a, B, b); A *= a;
    }
    sA[seg * 66 + ch] = A;
    sB[seg * 66 + ch] = B;
    __syncthreads();

    float u = 0.0f;
    #pragma unroll
    for (int q = 0; q < 15; ++q)
        if (q < seg) u = fmaf(sA[q * 66 + ch], u, sB[q * 66 + ch]);
    #pragma unroll 8
    for (int i = 0; i < NCH / 16; ++i) {
        const int idx = c0 + i;
        carry[idx * 64 + ch] = u;
        u = fmaf(Aar[idx * 64 + ch], u, Bar[idx * 64 + ch]);
    }
}

// ============================================================================
// Phase E v5: W2/B2 staging dropped — fragments read directly from w2bf
// (4 KB, L1-resident). LDS = Zs + seg + ucur ~ 14 KB. Same structure as v4
// otherwise: top-of-loop prefetch into n*, one barrier per subtile.
// ============================================================================
__global__ __launch_bounds__(256, 4)
void ephase(const uint4* __restrict__ abg, const float* __restrict__ carry,
            const short* __restrict__ w2bf, const float* __restrict__ B2,
            float* __restrict__ out)
{
    __shared__ __align__(16) short Zs[SUB * 72];       // z bf16 [m][k] 9.2KB
    __shared__ float segA[2 * 4 * 66], segB[2 * 4 * 66];
    __shared__ float ucur[2 * 64];

    const int tid  = threadIdx.x;
    const int c    = blockIdx.x;
    const int wave = tid >> 6;
    const int lane = tid & 63;
    const int quad = lane >> 4;
    const int lr   = lane & 15;

    if (tid < 64) ucur[tid] = carry[c * 64 + tid];     // ucur[0][*]
    // bias per lane
    const float b2a = B2[lr], b2b = B2[16 + lr];

    const uint4* ag = abg + (size_t)c * (NSUB * 16 * 64);
    uint4 r0 = ag[(wave * 4 + 0) * 64 + lane];
    uint4 r1 = ag[(wave * 4 + 1) * 64 + lane];
    uint4 r2 = ag[(wave * 4 + 2) * 64 + lane];
    uint4 r3 = ag[(wave * 4 + 3) * 64 + lane];

    for (int s = 0; s < NSUB; ++s) {
        const int pb = (s & 1) * 264;                  // seg buffer parity

        // ---- issue next subtile's ab loads FIRST (full-body latency window) ----
        uint4 n0, n1, n2, n3;
        if (s + 1 < NSUB) {
            const uint4* an = ag + (size_t)(s + 1) * (16 * 64);
            n0 = an[(wave * 4 + 0) * 64 + lane];
            n1 = an[(wave * 4 + 1) * 64 + lane];
            n2 = an[(wave * 4 + 2) * 64 + lane];
            n3 = an[(wave * 4 + 3) * 64 + lane];
        }

        // ---- compose own 16 rows from registers ----
        float A = 1.0f, Bv = 0.0f; float2 f;
#define CSTEP(W) { f = unpackbf2(W); Bv = fmaf(f.x, Bv, f.y); A *= f.x; }
        CSTEP(r0.x) CSTEP(r0.y) CSTEP(r0.z) CSTEP(r0.w)
        CSTEP(r1.x) CSTEP(r1.y) CSTEP(r1.z) CSTEP(r1.w)
        CSTEP(r2.x) CSTEP(r2.y) CSTEP(r2.z) CSTEP(r2.w)
        CSTEP(r3.x) CSTEP(r3.y) CSTEP(r3.z) CSTEP(r3.w)
#undef CSTEP
        segA[pb + wave * 66 + lane] = A;
        segB[pb + wave * 66 + lane] = Bv;
        __syncthreads();   // the only barrier per subtile

        // ---- per-wave prefix from carry-in ----
        float u = ucur[(s & 1) * 64 + lane];
        #pragma unroll
        for (int q = 0; q < 3; ++q)
            if (q < wave) u = fmaf(segA[pb + q * 66 + lane], u, segB[pb + q * 66 + lane]);

        // ---- emit z into own 16-row band of Zs ----
        int t = 0;
#define ESTEP(W) { Zs[(wave * 16 + t) * 72 + lane] = (short)f2bf(u); \
                   f = unpackbf2(W); u = fmaf(f.x, u, f.y); ++t; }
        ESTEP(r0.x) ESTEP(r0.y) ESTEP(r0.z) ESTEP(r0.w)
        ESTEP(r1.x) ESTEP(r1.y) ESTEP(r1.z) ESTEP(r1.w)
        ESTEP(r2.x) ESTEP(r2.y) ESTEP(r2.z) ESTEP(r2.w)
        ESTEP(r3.x) ESTEP(r3.y) ESTEP(r3.z) ESTEP(r3.w)
#undef ESTEP
        if (wave == 3) ucur[((s + 1) & 1) * 64 + lane] = u;   // other parity

        // ---- out = Z @ W2 + B2 via MFMA (reads own band only) ----
        const short8 za0 = *(const short8*)&Zs[(wave * 16 + lr) * 72 + quad * 8];
        const short8 za1 = *(const short8*)&Zs[(wave * 16 + lr) * 72 + quad * 8 + 32];
        const size_t row0g = (size_t)c * CHUNK + (size_t)s * SUB;
        #pragma unroll
        for (int nt = 0; nt < 2; ++nt) {
            f32x4 cc;
            float b = nt ? b2b : b2a;
            cc[0] = b; cc[1] = b; cc[2] = b; cc[3] = b;
            const short8 b0 = *(const short8*)&w2bf[(nt * 16 + lr) * 64 + quad * 8];
            const short8 b1 = *(const short8*)&w2bf[(nt * 16 + lr) * 64 + quad * 8 + 32];
            cc = __builtin_amdgcn_mfma_f32_16x16x32_bf16(za0, b0, cc, 0, 0, 0);
            cc = __builtin_amdgcn_mfma_f32_16x16x32_bf16(za1, b1, cc, 0, 0, 0);
            #pragma unroll
            for (int r = 0; r < 4; ++r) {
                int m = wave * 16 + quad * 4 + r;
                out[(row0g + m) * 32 + nt * 16 + lr] = cc[r];
            }
        }
        if (s + 1 < NSUB) { r0 = n0; r1 = n1; r2 = n2; r3 = n3; }
        // no trailing barrier: seg/ucur are parity double-buffered; Zs is
        // same-wave only.
    }
}

extern "C" void kernel_launch(void* const* d_in, const int* in_sizes, int n_in,
                              void* d_out, int out_size, void* d_ws, size_t ws_size,
                              hipStream_t stream)
{
    const float* x  = (const float*)d_in[0];
    const float* W1 = (const float*)d_in[1];
    const float* B1 = (const float*)d_in[2];
    const float* W2 = (const float*)d_in[3];
    const float* B2 = (const float*)d_in[4];
    float* out = (float*)d_out;

    float* Aar   = (float*)d_ws;                // NCH*64
    float* Bar   = Aar + NCH * 64;              // NCH*64
    float* carry = Bar + NCH * 64;              // NCH*64
    uint4* abg   = (uint4*)(carry + NCH * 64);  // TT*64*4 B = 134.2 MB packed ab
    short* w1bf  = (short*)(abg + (size_t)TT * 64 / 4);  // 16 KB
    short* w2bf  = w1bf + 128 * 64;                      // 4 KB

    prep<<<1, 256, 0, stream>>>(W1, W2, w1bf, w2bf);
    aphase<<<NCH, 256, 0, stream>>>(x, w1bf, B1, Aar, Bar, abg);
    carry_scan<<<1, 1024, 0, stream>>>(Aar, Bar, carry);
    ephase<<<NCH, 256, 0, stream>>>(abg, carry, w2bf, B2, out);
}

// Round 7
// 314.232 us; speedup vs baseline: 1.0272x; 1.0272x over previous
//
#include <hip/hip_runtime.h>

#define TT    524288
#define CHUNK 256
#define NCH   (TT / CHUNK)     // 2048 chunks -> 8 blocks/CU available
#define SUB   64               // subtile rows
#define NSUB  (CHUNK / SUB)    // 4

typedef __attribute__((ext_vector_type(8))) short short8;
typedef __attribute__((ext_vector_type(4))) float f32x4;

__device__ __forceinline__ unsigned short f2bf(float f) {
    union { float f; unsigned u; } v; v.f = f;
    unsigned r = v.u + 0x7FFFu + ((v.u >> 16) & 1u);   // RTNE
    return (unsigned short)(r >> 16);
}
// pack (a,b) -> bf16(a) | bf16(b)<<16
__device__ __forceinline__ unsigned packbf2(float a, float b) {
    union { float f; unsigned u; } va, vb; va.f = a; vb.f = b;
    unsigned ra = va.u + 0x7FFFu + ((va.u >> 16) & 1u);
    unsigned rb = vb.u + 0x7FFFu + ((vb.u >> 16) & 1u);
    return (ra >> 16) | (rb & 0xFFFF0000u);
}
__device__ __forceinline__ float2 unpackbf2(unsigned w) {
    union { unsigned u; float f; } a, b;
    a.u = w << 16; b.u = w & 0xFFFF0000u;
    return make_float2(a.f, b.f);
}
__device__ __forceinline__ float sigf(float v) {
    return __builtin_amdgcn_rcpf(1.0f + __expf(-v));   // v_exp + v_rcp
}

union U8 { uint4 u4; short8 s8; };

// ============================================================================
// Phase A v7 = v4 structure at CHUNK=256: wave w owns subtile w (64 rows),
// fi = 4 row-tiles. W1t staged in LDS (v4-proven faster than global frags).
// Register band-map + ordered shfl_xor tree; zero loop barriers.
// LDS = 27.4 KB -> 5 blocks/CU; grid 2048 = 8 blocks/CU available.
// ============================================================================
__global__ __launch_bounds__(256, 3)
void aphase(const float* __restrict__ x, const float* __restrict__ W1,
            const float* __restrict__ B1,
            float* __restrict__ Aout, float* __restrict__ Bout,
            uint4* __restrict__ abg)
{
    __shared__ __align__(16) short W1t[128 * 72];   // W1^T bf16 [n][k] 18.4KB
    __shared__ float    B1s[128];
    __shared__ float    segA[16 * 66], segB[16 * 66]; // band maps 8.4KB

    const int tid  = threadIdx.x;
    const int c    = blockIdx.x;
    const int wave = tid >> 6;
    const int lane = tid & 63;
    const int quad = lane >> 4;
    const int lr   = lane & 15;

    for (int i = tid; i < 2048; i += 256) {
        float4 w4 = ((const float4*)W1)[i];
        int k = i >> 5, n0 = (i & 31) * 4;
        W1t[(n0 + 0) * 72 + k] = (short)f2bf(w4.x);
        W1t[(n0 + 1) * 72 + k] = (short)f2bf(w4.y);
        W1t[(n0 + 2) * 72 + k] = (short)f2bf(w4.z);
        W1t[(n0 + 3) * 72 + k] = (short)f2bf(w4.w);
    }
    if (tid < 128) B1s[tid] = B1[tid];
    __syncthreads();   // staging barrier (1 of 2)

    // hoist bias to registers
    float bb[8];
    #pragma unroll
    for (int j = 0; j < 8; ++j) bb[j] = B1s[j * 16 + lr];

    const float* xbase = x + (size_t)c * CHUNK * 64;

    // fragment load address for row-tile rt of this wave's subtile
    #define FRAGP(rt) ((const float4*)(xbase + (size_t)((wave * 64 + (rt) * 16 + lr)) * 64) + quad * 2)

    // prologue: load fi=0
    const float4* p0 = FRAGP(0);
    float4 c0 = p0[0], c1 = p0[1], c2 = p0[8], c3 = p0[9];

    const bool h1 = (quad & 1) != 0;   // hi half of the quad pair
    const bool h2 = (quad & 2) != 0;   // hi half of the 16-row block

    for (int fi = 0; fi < NSUB; ++fi) {
        const int ss = wave;
        const int rt = fi;

        // ---- convert current 16-row tile to bf16 A-frags (frees c0..c3) ----
        U8 ua, ub;
        ua.u4 = make_uint4(packbf2(c0.x, c0.y), packbf2(c0.z, c0.w),
                           packbf2(c1.x, c1.y), packbf2(c1.z, c1.w));
        ub.u4 = make_uint4(packbf2(c2.x, c2.y), packbf2(c2.z, c2.w),
                           packbf2(c3.x, c3.y), packbf2(c3.z, c3.w));
        const short8 a0 = ua.s8, a1 = ub.s8;

        // ---- immediately reload NEXT tile into c* (full-body latency window) ----
        if (fi < NSUB - 1) {
            const float4* np = FRAGP(fi + 1);
            c0 = np[0]; c1 = np[1]; c2 = np[8]; c3 = np[9];
        }

        // ---- MFMA 16 rows x 128 cols ----
        f32x4 acc[8];
        #pragma unroll
        for (int j = 0; j < 8; ++j) {
            acc[j][0] = bb[j]; acc[j][1] = bb[j]; acc[j][2] = bb[j]; acc[j][3] = bb[j];
        }
        #pragma unroll
        for (int j = 0; j < 8; ++j) {
            const short8 b0 = *(const short8*)&W1t[(j * 16 + lr) * 72 + quad * 8];
            const short8 b1 = *(const short8*)&W1t[(j * 16 + lr) * 72 + quad * 8 + 32];
            acc[j] = __builtin_amdgcn_mfma_f32_16x16x32_bf16(a0, b0, acc[j], 0, 0, 0);
            acc[j] = __builtin_amdgcn_mfma_f32_16x16x32_bf16(a1, b1, acc[j], 0, 0, 0);
        }

        // ---- sigmoid; a=l*r, b=1-l; pack ----
        unsigned pk[4][4];
        #pragma unroll
        for (int j = 0; j < 4; ++j) {
            #pragma unroll
            for (int r = 0; r < 4; ++r) {
                float hl = sigf(acc[j][r]);
                float hr = sigf(acc[j + 4][r]);
                pk[j][r] = packbf2(hl * hr, 1.0f - hl);
            }
        }

        // ---- export ab directly from registers ----
        {
            uint4* dstq = abg + ((size_t)((c * NSUB + ss) * 16 + rt * 4 + quad)) * 64 + lr;
            #pragma unroll
            for (int j = 0; j < 4; ++j)
                dstq[j * 16] = make_uint4(pk[j][0], pk[j][1], pk[j][2], pk[j][3]);
        }

        // ---- band map fully in registers ----
        float Aa[4], Ba[4];
        #pragma unroll
        for (int j = 0; j < 4; ++j) {
            float A = 1.0f, Bv = 0.0f;
            #pragma unroll
            for (int r = 0; r < 4; ++r) {
                float2 f = unpackbf2(pk[j][r]);
                Bv = fmaf(f.x, Bv, f.y); A *= f.x;
            }
            Aa[j] = A; Ba[j] = Bv;
        }
        // ordered tree over quads: combine(hi,lo): A=A_hi*A_lo; B=fmaf(A_hi,B_lo,B_hi)
        #pragma unroll
        for (int j = 0; j < 4; ++j) {
            float Ap = __shfl_xor(Aa[j], 16);
            float Bp = __shfl_xor(Ba[j], 16);
            float Ahi = h1 ? Aa[j] : Ap;
            float Blo = h1 ? Bp    : Ba[j];
            float Bhi = h1 ? Ba[j] : Bp;
            Aa[j] *= Ap;
            Ba[j] = fmaf(Ahi, Blo, Bhi);

            Ap = __shfl_xor(Aa[j], 32);
            Bp = __shfl_xor(Ba[j], 32);
            Ahi = h2 ? Aa[j] : Ap;
            Blo = h2 ? Bp    : Ba[j];
            Bhi = h2 ? Ba[j] : Bp;
            Aa[j] *= Ap;
            Ba[j] = fmaf(Ahi, Blo, Bhi);
        }
        const float Asel = (quad == 0) ? Aa[0] : (quad == 1) ? Aa[1]
                         : (quad == 2) ? Aa[2] : Aa[3];
        const float Bsel = (quad == 0) ? Ba[0] : (quad == 1) ? Ba[1]
                         : (quad == 2) ? Ba[2] : Ba[3];
        const int band = ss * 4 + rt;      // wave*4+fi in [0,16)
        segA[band * 66 + lane] = Asel;
        segB[band * 66 + lane] = Bsel;
    }
    #undef FRAGP

    __syncthreads();   // (2 of 2)
    if (tid < 64) {
        float sA = 1.0f, sB = 0.0f;
        // serial fold over all 16 bands in row order
        for (int b = 0; b < 16; ++b) {
            float A2 = segA[b * 66 + tid], B2v = segB[b * 66 + tid];
            sB = fmaf(A2, sB, B2v); sA *= A2;
        }
        Aout[c * 64 + tid] = sA; Bout[c * 64 + tid] = sB;
    }
}

// ============================================================================
// Carry scan across 2048 chunk maps: 16 parallel segments of 128 (1024 thr).
// ============================================================================
__global__ void carry_scan(const float* __restrict__ Aar, const float* __restrict__ Bar,
                           float* __restrict__ carry)
{
    __shared__ float sA[16 * 66], sB[16 * 66];
    const int tid = threadIdx.x;
    const int ch = tid & 63, seg = tid >> 6;       // 16 segments
    const int c0 = seg * (NCH / 16);

    float A = 1.0f, B = 0.0f;
    #pragma unroll 8
    for (int i = 0; i < NCH / 16; ++i) {
        const int idx = c0 + i;
        const float a = Aar[idx * 64 + ch];
        const float b = Bar[idx * 64 + ch];
        B = fmaf(a, B, b); A *= a;
    }
    sA[seg * 66 + ch] = A;
    sB[seg * 66 + ch] = B;
    __syncthreads();

    float u = 0.0f;
    #pragma unroll
    for (int q = 0; q < 15; ++q)
        if (q < seg) u = fmaf(sA[q * 66 + ch], u, sB[q * 66 + ch]);
    #pragma unroll 8
    for (int i = 0; i < NCH / 16; ++i) {
        const int idx = c0 + i;
        carry[idx * 64 + ch] = u;
        u = fmaf(Aar[idx * 64 + ch], u, Bar[idx * 64 + ch]);
    }
}

// ============================================================================
// Phase E v7 = v4 structure at CHUNK=256 (NSUB=4): W2t staged in LDS,
// top-of-loop prefetch into n*, one barrier per subtile, parity-double-
// buffered seg/ucur. LDS ~18.5 KB -> 8 blocks/CU; grid 2048 = 8/CU.
// ============================================================================
__global__ __launch_bounds__(256, 4)
void ephase(const uint4* __restrict__ abg, const float* __restrict__ carry,
            const float* __restrict__ W2, const float* __restrict__ B2,
            float* __restrict__ out)
{
    __shared__ __align__(16) short Zs[SUB * 72];       // z bf16 [m][k] 9.2KB
    __shared__ float segA[2 * 4 * 66], segB[2 * 4 * 66];
    __shared__ __align__(16) short W2t[32 * 72];       // W2^T bf16 [n][k]
    __shared__ float B2s[32];
    __shared__ float ucur[2 * 64];

    const int tid  = threadIdx.x;
    const int c    = blockIdx.x;
    const int wave = tid >> 6;
    const int lane = tid & 63;
    const int quad = lane >> 4;
    const int lr   = lane & 15;

    for (int i = tid; i < 512; i += 256) {
        float4 w4 = ((const float4*)W2)[i];
        int k = i >> 3, n0 = (i & 7) * 4;
        W2t[(n0 + 0) * 72 + k] = (short)f2bf(w4.x);
        W2t[(n0 + 1) * 72 + k] = (short)f2bf(w4.y);
        W2t[(n0 + 2) * 72 + k] = (short)f2bf(w4.z);
        W2t[(n0 + 3) * 72 + k] = (short)f2bf(w4.w);
    }
    if (tid < 32) B2s[tid] = B2[tid];
    if (tid < 64) ucur[tid] = carry[c * 64 + tid];     // ucur[0][*]
    // first reads of all staged LDS happen after the s=0 barrier below.

    const uint4* ag = abg + (size_t)c * (NSUB * 16 * 64);
    uint4 r0 = ag[(wave * 4 + 0) * 64 + lane];
    uint4 r1 = ag[(wave * 4 + 1) * 64 + lane];
    uint4 r2 = ag[(wave * 4 + 2) * 64 + lane];
    uint4 r3 = ag[(wave * 4 + 3) * 64 + lane];

    for (int s = 0; s < NSUB; ++s) {
        const int pb = (s & 1) * 264;                  // seg buffer parity

        // ---- issue next subtile's ab loads FIRST (full-body latency window) ----
        uint4 n0, n1, n2, n3;
        if (s + 1 < NSUB) {
            const uint4* an = ag + (size_t)(s + 1) * (16 * 64);
            n0 = an[(wave * 4 + 0) * 64 + lane];
            n1 = an[(wave * 4 + 1) * 64 + lane];
            n2 = an[(wave * 4 + 2) * 64 + lane];
            n3 = an[(wave * 4 + 3) * 64 + lane];
        }

        // ---- compose own 16 rows from registers ----
        float A = 1.0f, Bv = 0.0f; float2 f;
#define CSTEP(W) { f = unpackbf2(W); Bv = fmaf(f.x, Bv, f.y); A *= f.x; }
        CSTEP(r0.x) CSTEP(r0.y) CSTEP(r0.z) CSTEP(r0.w)
        CSTEP(r1.x) CSTEP(r1.y) CSTEP(r1.z) CSTEP(r1.w)
        CSTEP(r2.x) CSTEP(r2.y) CSTEP(r2.z) CSTEP(r2.w)
        CSTEP(r3.x) CSTEP(r3.y) CSTEP(r3.z) CSTEP(r3.w)
#undef CSTEP
        segA[pb + wave * 66 + lane] = A;
        segB[pb + wave * 66 + lane] = Bv;
        __syncthreads();   // the only barrier per subtile

        // ---- per-wave prefix from carry-in ----
        float u = ucur[(s & 1) * 64 + lane];
        #pragma unroll
        for (int q = 0; q < 3; ++q)
            if (q < wave) u = fmaf(segA[pb + q * 66 + lane], u, segB[pb + q * 66 + lane]);

        // ---- emit z into own 16-row band of Zs ----
        int t = 0;
#define ESTEP(W) { Zs[(wave * 16 + t) * 72 + lane] = (short)f2bf(u); \
                   f = unpackbf2(W); u = fmaf(f.x, u, f.y); ++t; }
        ESTEP(r0.x) ESTEP(r0.y) ESTEP(r0.z) ESTEP(r0.w)
        ESTEP(r1.x) ESTEP(r1.y) ESTEP(r1.z) ESTEP(r1.w)
        ESTEP(r2.x) ESTEP(r2.y) ESTEP(r2.z) ESTEP(r2.w)
        ESTEP(r3.x) ESTEP(r3.y) ESTEP(r3.z) ESTEP(r3.w)
#undef ESTEP
        if (wave == 3) ucur[((s + 1) & 1) * 64 + lane] = u;   // other parity

        // ---- out = Z @ W2 + B2 via MFMA (reads own band only) ----
        const short8 za0 = *(const short8*)&Zs[(wave * 16 + lr) * 72 + quad * 8];
        const short8 za1 = *(const short8*)&Zs[(wave * 16 + lr) * 72 + quad * 8 + 32];
        const size_t row0g = (size_t)c * CHUNK + (size_t)s * SUB;
        #pragma unroll
        for (int nt = 0; nt < 2; ++nt) {
            f32x4 cc;
            float b = B2s[nt * 16 + lr];
            cc[0] = b; cc[1] = b; cc[2] = b; cc[3] = b;
            const short8 b0 = *(const short8*)&W2t[(nt * 16 + lr) * 72 + quad * 8];
            const short8 b1 = *(const short8*)&W2t[(nt * 16 + lr) * 72 + quad * 8 + 32];
            cc = __builtin_amdgcn_mfma_f32_16x16x32_bf16(za0, b0, cc, 0, 0, 0);
            cc = __builtin_amdgcn_mfma_f32_16x16x32_bf16(za1, b1, cc, 0, 0, 0);
            #pragma unroll
            for (int r = 0; r < 4; ++r) {
                int m = wave * 16 + quad * 4 + r;
                out[(row0g + m) * 32 + nt * 16 + lr] = cc[r];
            }
        }
        if (s + 1 < NSUB) { r0 = n0; r1 = n1; r2 = n2; r3 = n3; }
        // no trailing barrier: seg/ucur are parity double-buffered; Zs is
        // same-wave only.
    }
}

extern "C" void kernel_launch(void* const* d_in, const int* in_sizes, int n_in,
                              void* d_out, int out_size, void* d_ws, size_t ws_size,
                              hipStream_t stream)
{
    const float* x  = (const float*)d_in[0];
    const float* W1 = (const float*)d_in[1];
    const float* B1 = (const float*)d_in[2];
    const float* W2 = (const float*)d_in[3];
    const float* B2 = (const float*)d_in[4];
    float* out = (float*)d_out;

    float* Aar   = (float*)d_ws;                // NCH*64
    float* Bar   = Aar + NCH * 64;              // NCH*64
    float* carry = Bar + NCH * 64;              // NCH*64
    uint4* abg   = (uint4*)(carry + NCH * 64);  // TT*64*4 B = 134.2 MB packed ab

    aphase<<<NCH, 256, 0, stream>>>(x, W1, B1, Aar, Bar, abg);
    carry_scan<<<1, 1024, 0, stream>>>(Aar, Bar, carry);
    ephase<<<NCH, 256, 0, stream>>>(abg, carry, W2, B2, out);
}

// Round 8
// 302.879 us; speedup vs baseline: 1.0657x; 1.0375x over previous
//
#include <hip/hip_runtime.h>

#define TT    524288
#define CHUNK 512
#define NCH   (TT / CHUNK)     // 1024 chunks
#define SUB   64               // subtile rows
#define NSUB  (CHUNK / SUB)    // 8

typedef __attribute__((ext_vector_type(8))) short short8;
typedef __attribute__((ext_vector_type(4))) float f32x4;

__device__ __forceinline__ unsigned short f2bf(float f) {
    union { float f; unsigned u; } v; v.f = f;
    unsigned r = v.u + 0x7FFFu + ((v.u >> 16) & 1u);   // RTNE
    return (unsigned short)(r >> 16);
}
// pack (a,b) -> bf16(a) | bf16(b)<<16
__device__ __forceinline__ unsigned packbf2(float a, float b) {
    union { float f; unsigned u; } va, vb; va.f = a; vb.f = b;
    unsigned ra = va.u + 0x7FFFu + ((va.u >> 16) & 1u);
    unsigned rb = vb.u + 0x7FFFu + ((vb.u >> 16) & 1u);
    return (ra >> 16) | (rb & 0xFFFF0000u);
}
__device__ __forceinline__ float2 unpackbf2(unsigned w) {
    union { unsigned u; float f; } a, b;
    a.u = w << 16; b.u = w & 0xFFFF0000u;
    return make_float2(a.f, b.f);
}
__device__ __forceinline__ float sigf(float v) {
    return __builtin_amdgcn_rcpf(1.0f + __expf(-v));   // v_exp + v_rcp
}

union U8 { uint4 u4; short8 s8; };

// async 16B global -> LDS DMA (no VGPR round-trip). LDS dest must be
// wave-uniform base; HW adds lane*16.
__device__ __forceinline__ void gl_lds16(const void* g, void* l) {
    __builtin_amdgcn_global_load_lds(
        (__attribute__((address_space(1))) void*)g,
        (__attribute__((address_space(3))) void*)l, 16, 0, 0);
}

// ============================================================================
// prep: one-time W1 f32 -> bf16 transposed + 16B-unit XOR-swizzled layout.
// w1swz[n*64 + ((k>>3)^(n&7))*8 + (k&7)] = bf16(W1[k][n]), n in [0,128), k in [0,64).
// So aphase can stage it into LDS with a LINEAR (conflict-free) copy and read
// B-frags conflict-free without the +8 pad.
// ============================================================================
__global__ void prep(const float* __restrict__ W1, short* __restrict__ w1swz)
{
    const int tid = threadIdx.x;
    for (int i = tid; i < 2048; i += 256) {
        float4 w4 = ((const float4*)W1)[i];
        int k = i >> 5, n0 = (i & 31) * 4;
        int kb = k >> 3, kr = k & 7;
        float v[4] = { w4.x, w4.y, w4.z, w4.w };
        #pragma unroll
        for (int j = 0; j < 4; ++j) {
            int n = n0 + j;
            w1swz[n * 64 + ((kb ^ (n & 7)) * 8) + kr] = (short)f2bf(v[j]);
        }
    }
}

// ============================================================================
// Phase A v8: wave-private ASYNC x staging via global_load_lds.
//  - wave w owns subtiles {w, w+4}; 8 row-tiles of 16 rows; per tile 4 DMAs
//    (1 KB each) into a private 3-deep LDS ring (no barriers in the loop).
//  - uniform per-iteration VMEM count (4 DMA + 4 abg stores; tail iterations
//    issue wrap-around dummy DMAs) => counted `s_waitcnt vmcnt(8)` keeps the
//    previous iteration's 8 ops in flight and guarantees this tile's DMAs done.
//  - x tiles and W1 are 16B-unit XOR-swizzled (u ^= row&7): conflict-free
//    ds reads; all LDS writes linear.
//  - band maps accumulated per wave in registers (seg = 8 entries only).
// LDS = 16K(W1s) + 48K(x ring) + 4.2K(seg) = 68.2 KB -> 2 blocks/CU; the
// async depth (8 KB in flight/wave) replaces occupancy for read latency.
// ============================================================================
__global__ __launch_bounds__(256, 2)
void aphase(const float* __restrict__ x, const short* __restrict__ w1swz,
            const float* __restrict__ B1,
            float* __restrict__ Aout, float* __restrict__ Bout,
            uint4* __restrict__ abg)
{
    __shared__ __align__(16) short W1s[128 * 64];     // 16 KB, swizzled
    __shared__ __align__(16) float xs[4][3][16 * 64]; // 48 KB wave-private ring
    __shared__ float segA[8 * 65], segB[8 * 65];      // 4.2 KB

    const int tid  = threadIdx.x;
    const int c    = blockIdx.x;
    const int wave = tid >> 6;
    const int lane = tid & 63;
    const int quad = lane >> 4;
    const int lr   = lane & 15;
    const int rlo  = lane >> 4;    // DMA: row subgroup 0..3
    const int usrc = lane & 15;    // DMA: dest 16B-unit within row

    // ---- stage swizzled W1 (linear b128 copy: conflict-free) ----
    {
        const uint4* src = (const uint4*)w1swz;
        uint4* dst = (uint4*)W1s;
        #pragma unroll
        for (int i = 0; i < 4; ++i) dst[tid + 256 * i] = src[tid + 256 * i];
    }
    float bb[8];
    #pragma unroll
    for (int j = 0; j < 8; ++j) bb[j] = B1[j * 16 + lr];
    __syncthreads();   // W1s visible; also drains all prologue vmem (clean slate)

    const float* xbase = x + (size_t)c * CHUNK * 64;

    // issue the 4 DMAs for row-tile (ss,rt) into ring buffer bu of this wave.
    // source is pre-swizzled per-lane so the linear DMA lands the swizzled layout.
    #define ISSUE_DMA(TT_, BU_) {                                              \
        const int ss_ = ((TT_) < 4) ? wave : (wave + 4);                       \
        const int rt_ = (TT_) & 3;                                             \
        float* lb_ = &xs[wave][(BU_)][0];                                      \
        _Pragma("unroll")                                                      \
        for (int d_ = 0; d_ < 4; ++d_) {                                       \
            const int rit_ = d_ * 4 + rlo;                                     \
            const float* g_ = xbase + (size_t)(ss_ * 64 + rt_ * 16 + rit_) * 64\
                              + ((usrc ^ (rit_ & 7)) << 2);                    \
            gl_lds16(g_, lb_ + d_ * 256);                                      \
        } }

    // prologue: tiles 0,1 in flight; drain tile 0 (leave tile 1's 4 in flight)
    ISSUE_DMA(0, 0)
    ISSUE_DMA(1, 1)
    asm volatile("s_waitcnt vmcnt(4)" ::: "memory");

    const bool h1 = (quad & 1) != 0;
    const bool h2 = (quad & 2) != 0;
    float sAw = 1.0f, sBw = 0.0f;

    #pragma unroll
    for (int fi = 0; fi < 8; ++fi) {
        const int ss = (fi < 4) ? wave : (wave + 4);
        const int rt = fi & 3;
        const int bu = fi % 3;

        // counted wait: keeps previous iteration's (4 stores + 4 DMA) in
        // flight, guarantees this tile's 4 DMAs (issued 2 iterations ago
        // for fi>=2, prologue otherwise) have landed in LDS.
        asm volatile("s_waitcnt vmcnt(8)" ::: "memory");
        __builtin_amdgcn_sched_barrier(0);

        // ---- read own 16-row tile (swizzled) from LDS ----
        const float* xr = &xs[wave][bu][0];
        const int u0 = (quad * 2) ^ (lr & 7);
        const float4 c0 = *(const float4*)&xr[lr * 64 + u0 * 4];
        const float4 c1 = *(const float4*)&xr[lr * 64 + (u0 ^ 1) * 4];
        const float4 c2 = *(const float4*)&xr[lr * 64 + (u0 + 8) * 4];
        const float4 c3 = *(const float4*)&xr[lr * 64 + ((u0 ^ 1) + 8) * 4];

        // ---- convert to bf16 A-frags ----
        U8 ua, ub;
        ua.u4 = make_uint4(packbf2(c0.x, c0.y), packbf2(c0.z, c0.w),
                           packbf2(c1.x, c1.y), packbf2(c1.z, c1.w));
        ub.u4 = make_uint4(packbf2(c2.x, c2.y), packbf2(c2.z, c2.w),
                           packbf2(c3.x, c3.y), packbf2(c3.z, c3.w));
        const short8 a0 = ua.s8, a1 = ub.s8;

        // ---- MFMA 16 rows x 128 cols (W1s swizzled reads: conflict-free) ----
        f32x4 acc[8];
        #pragma unroll
        for (int j = 0; j < 8; ++j) {
            acc[j][0] = bb[j]; acc[j][1] = bb[j]; acc[j][2] = bb[j]; acc[j][3] = bb[j];
        }
        const int ub0 = quad ^ (lr & 7);
        #pragma unroll
        for (int j = 0; j < 8; ++j) {
            const int rw = j * 16 + lr;
            const short8 b0 = *(const short8*)&W1s[rw * 64 + ub0 * 8];
            const short8 b1 = *(const short8*)&W1s[rw * 64 + (ub0 ^ 4) * 8];
            acc[j] = __builtin_amdgcn_mfma_f32_16x16x32_bf16(a0, b0, acc[j], 0, 0, 0);
            acc[j] = __builtin_amdgcn_mfma_f32_16x16x32_bf16(a1, b1, acc[j], 0, 0, 0);
        }

        // ---- sigmoid; a=l*r, b=1-l; pack ----
        unsigned pk[4][4];
        #pragma unroll
        for (int j = 0; j < 4; ++j) {
            #pragma unroll
            for (int r = 0; r < 4; ++r) {
                float hl = sigf(acc[j][r]);
                float hr = sigf(acc[j + 4][r]);
                pk[j][r] = packbf2(hl * hr, 1.0f - hl);
            }
        }

        // ---- export ab (4 stores) ----
        {
            uint4* dstq = abg + ((size_t)((c * NSUB + ss) * 16 + rt * 4 + quad)) * 64 + lr;
            #pragma unroll
            for (int j = 0; j < 4; ++j)
                dstq[j * 16] = make_uint4(pk[j][0], pk[j][1], pk[j][2], pk[j][3]);
        }

        // pin [stores][DMA] issue order (vmcnt counting), then issue tile fi+2
        // into ring slot (fi+2)%3 (never the buffer being read this iteration).
        asm volatile("" ::: "memory");
        {
            const int t2 = (fi + 2) & 7;     // wrap-around dummies at fi=6,7
            ISSUE_DMA(t2, (fi + 2) % 3)
        }

        // ---- band map in registers: per-lane 4-row fold + ordered shfl tree ----
        float Aa[4], Ba[4];
        #pragma unroll
        for (int j = 0; j < 4; ++j) {
            float A = 1.0f, Bv = 0.0f;
            #pragma unroll
            for (int r = 0; r < 4; ++r) {
                float2 f = unpackbf2(pk[j][r]);
                Bv = fmaf(f.x, Bv, f.y); A *= f.x;
            }
            Aa[j] = A; Ba[j] = Bv;
        }
        #pragma unroll
        for (int j = 0; j < 4; ++j) {
            float Ap = __shfl_xor(Aa[j], 16);
            float Bp = __shfl_xor(Ba[j], 16);
            float Ahi = h1 ? Aa[j] : Ap;
            float Blo = h1 ? Bp    : Ba[j];
            float Bhi = h1 ? Ba[j] : Bp;
            Aa[j] *= Ap;
            Ba[j] = fmaf(Ahi, Blo, Bhi);

            Ap = __shfl_xor(Aa[j], 32);
            Bp = __shfl_xor(Ba[j], 32);
            Ahi = h2 ? Aa[j] : Ap;
            Blo = h2 ? Bp    : Ba[j];
            Bhi = h2 ? Ba[j] : Bp;
            Aa[j] *= Ap;
            Ba[j] = fmaf(Ahi, Blo, Bhi);
        }
        const float Asel = (quad == 0) ? Aa[0] : (quad == 1) ? Aa[1]
                         : (quad == 2) ? Aa[2] : Aa[3];
        const float Bsel = (quad == 0) ? Ba[0] : (quad == 1) ? Ba[1]
                         : (quad == 2) ? Ba[2] : Ba[3];

        // accumulate this wave's subtile map across its 4 row-tiles (row order)
        if (rt == 0) { sAw = Asel; sBw = Bsel; }
        else         { sBw = fmaf(Asel, sBw, Bsel); sAw *= Asel; }
        if (rt == 3) { segA[ss * 65 + lane] = sAw; segB[ss * 65 + lane] = sBw; }
    }
    #undef ISSUE_DMA

    __syncthreads();
    if (tid < 64) {
        float sA = 1.0f, sB = 0.0f;
        #pragma unroll
        for (int b = 0; b < 8; ++b) {   // subtile order = row order
            float A2 = segA[b * 65 + tid], B2v = segB[b * 65 + tid];
            sB = fmaf(A2, sB, B2v); sA *= A2;
        }
        Aout[c * 64 + tid] = sA; Bout[c * 64 + tid] = sB;
    }
}

// ============================================================================
// Carry scan across 1024 chunk maps: 16 parallel segments of 64 (1024 thr).
// ============================================================================
__global__ void carry_scan(const float* __restrict__ Aar, const float* __restrict__ Bar,
                           float* __restrict__ carry)
{
    __shared__ float sA[16 * 66], sB[16 * 66];
    const int tid = threadIdx.x;
    const int ch = tid & 63, seg = tid >> 6;       // 16 segments
    const int c0 = seg * (NCH / 16);

    float A = 1.0f, B = 0.0f;
    #pragma unroll 8
    for (int i = 0; i < NCH / 16; ++i) {
        const int idx = c0 + i;
        const float a = Aar[idx * 64 + ch];
        const float b = Bar[idx * 64 + ch];
        B = fmaf(a, B, b); A *= a;
    }
    sA[seg * 66 + ch] = A;
    sB[seg * 66 + ch] = B;
    __syncthreads();

    float u = 0.0f;
    #pragma unroll
    for (int q = 0; q < 15; ++q)
        if (q < seg) u = fmaf(sA[q * 66 + ch], u, sB[q * 66 + ch]);
    #pragma unroll 8
    for (int i = 0; i < NCH / 16; ++i) {
        const int idx = c0 + i;
        carry[idx * 64 + ch] = u;
        u = fmaf(Aar[idx * 64 + ch], u, Bar[idx * 64 + ch]);
    }
}

// ============================================================================
// Phase E: verbatim round-5 (best-total) version. Top-of-loop prefetch into
// n*, one barrier per subtile, parity double-buffered seg/ucur.
// ============================================================================
__global__ __launch_bounds__(256, 4)
void ephase(const uint4* __restrict__ abg, const float* __restrict__ carry,
            const float* __restrict__ W2, const float* __restrict__ B2,
            float* __restrict__ out)
{
    __shared__ __align__(16) short Zs[SUB * 72];       // z bf16 [m][k] 9.2KB
    __shared__ float segA[2 * 4 * 66], segB[2 * 4 * 66];
    __shared__ __align__(16) short W2t[32 * 72];       // W2^T bf16 [n][k]
    __shared__ float B2s[32];
    __shared__ float ucur[2 * 64];

    const int tid  = threadIdx.x;
    const int c    = blockIdx.x;
    const int wave = tid >> 6;
    const int lane = tid & 63;
    const int quad = lane >> 4;
    const int lr   = lane & 15;

    for (int i = tid; i < 512; i += 256) {
        float4 w4 = ((const float4*)W2)[i];
        int k = i >> 3, n0 = (i & 7) * 4;
        W2t[(n0 + 0) * 72 + k] = (short)f2bf(w4.x);
        W2t[(n0 + 1) * 72 + k] = (short)f2bf(w4.y);
        W2t[(n0 + 2) * 72 + k] = (short)f2bf(w4.z);
        W2t[(n0 + 3) * 72 + k] = (short)f2bf(w4.w);
    }
    if (tid < 32) B2s[tid] = B2[tid];
    if (tid < 64) ucur[tid] = carry[c * 64 + tid];     // ucur[0][*]
    // first reads of all staged LDS happen after the s=0 barrier below.

    const uint4* ag = abg + (size_t)c * (NSUB * 16 * 64);
    uint4 r0 = ag[(wave * 4 + 0) * 64 + lane];
    uint4 r1 = ag[(wave * 4 + 1) * 64 + lane];
    uint4 r2 = ag[(wave * 4 + 2) * 64 + lane];
    uint4 r3 = ag[(wave * 4 + 3) * 64 + lane];

    for (int s = 0; s < NSUB; ++s) {
        const int pb = (s & 1) * 264;                  // seg buffer parity

        // ---- issue next subtile's ab loads FIRST (full-body latency window) ----
        uint4 n0, n1, n2, n3;
        if (s + 1 < NSUB) {
            const uint4* an = ag + (size_t)(s + 1) * (16 * 64);
            n0 = an[(wave * 4 + 0) * 64 + lane];
            n1 = an[(wave * 4 + 1) * 64 + lane];
            n2 = an[(wave * 4 + 2) * 64 + lane];
            n3 = an[(wave * 4 + 3) * 64 + lane];
        }

        // ---- compose own 16 rows from registers ----
        float A = 1.0f, Bv = 0.0f; float2 f;
#define CSTEP(W) { f = unpackbf2(W); Bv = fmaf(f.x, Bv, f.y); A *= f.x; }
        CSTEP(r0.x) CSTEP(r0.y) CSTEP(r0.z) CSTEP(r0.w)
        CSTEP(r1.x) CSTEP(r1.y) CSTEP(r1.z) CSTEP(r1.w)
        CSTEP(r2.x) CSTEP(r2.y) CSTEP(r2.z) CSTEP(r2.w)
        CSTEP(r3.x) CSTEP(r3.y) CSTEP(r3.z) CSTEP(r3.w)
#undef CSTEP
        segA[pb + wave * 66 + lane] = A;
        segB[pb + wave * 66 + lane] = Bv;
        __syncthreads();   // the only barrier per subtile

        // ---- per-wave prefix from carry-in ----
        float u = ucur[(s & 1) * 64 + lane];
        #pragma unroll
        for (int q = 0; q < 3; ++q)
            if (q < wave) u = fmaf(segA[pb + q * 66 + lane], u, segB[pb + q * 66 + lane]);

        // ---- emit z into own 16-row band of Zs ----
        int t = 0;
#define ESTEP(W) { Zs[(wave * 16 + t) * 72 + lane] = (short)f2bf(u); \
                   f = unpackbf2(W); u = fmaf(f.x, u, f.y); ++t; }
        ESTEP(r0.x) ESTEP(r0.y) ESTEP(r0.z) ESTEP(r0.w)
        ESTEP(r1.x) ESTEP(r1.y) ESTEP(r1.z) ESTEP(r1.w)
        ESTEP(r2.x) ESTEP(r2.y) ESTEP(r2.z) ESTEP(r2.w)
        ESTEP(r3.x) ESTEP(r3.y) ESTEP(r3.z) ESTEP(r3.w)
#undef ESTEP
        if (wave == 3) ucur[((s + 1) & 1) * 64 + lane] = u;   // other parity

        // ---- out = Z @ W2 + B2 via MFMA (reads own band only) ----
        const short8 za0 = *(const short8*)&Zs[(wave * 16 + lr) * 72 + quad * 8];
        const short8 za1 = *(const short8*)&Zs[(wave * 16 + lr) * 72 + quad * 8 + 32];
        const size_t row0g = (size_t)c * CHUNK + (size_t)s * SUB;
        #pragma unroll
        for (int nt = 0; nt < 2; ++nt) {
            f32x4 cc;
            float b = B2s[nt * 16 + lr];
            cc[0] = b; cc[1] = b; cc[2] = b; cc[3] = b;
            const short8 b0 = *(const short8*)&W2t[(nt * 16 + lr) * 72 + quad * 8];
            const short8 b1 = *(const short8*)&W2t[(nt * 16 + lr) * 72 + quad * 8 + 32];
            cc = __builtin_amdgcn_mfma_f32_16x16x32_bf16(za0, b0, cc, 0, 0, 0);
            cc = __builtin_amdgcn_mfma_f32_16x16x32_bf16(za1, b1, cc, 0, 0, 0);
            #pragma unroll
            for (int r = 0; r < 4; ++r) {
                int m = wave * 16 + quad * 4 + r;
                out[(row0g + m) * 32 + nt * 16 + lr] = cc[r];
            }
        }
        if (s + 1 < NSUB) { r0 = n0; r1 = n1; r2 = n2; r3 = n3; }
        // no trailing barrier: seg/ucur are parity double-buffered; Zs is
        // same-wave only.
    }
}

extern "C" void kernel_launch(void* const* d_in, const int* in_sizes, int n_in,
                              void* d_out, int out_size, void* d_ws, size_t ws_size,
                              hipStream_t stream)
{
    const float* x  = (const float*)d_in[0];
    const float* W1 = (const float*)d_in[1];
    const float* B1 = (const float*)d_in[2];
    const float* W2 = (const float*)d_in[3];
    const float* B2 = (const float*)d_in[4];
    float* out = (float*)d_out;

    float* Aar   = (float*)d_ws;                // NCH*64
    float* Bar   = Aar + NCH * 64;              // NCH*64
    float* carry = Bar + NCH * 64;              // NCH*64
    uint4* abg   = (uint4*)(carry + NCH * 64);  // TT*64*4 B = 134.2 MB packed ab
    short* w1swz = (short*)(abg + (size_t)TT * 16);  // 16 KB swizzled W1

    prep<<<1, 256, 0, stream>>>(W1, w1swz);
    aphase<<<NCH, 256, 0, stream>>>(x, w1swz, B1, Aar, Bar, abg);
    carry_scan<<<1, 1024, 0, stream>>>(Aar, Bar, carry);
    ephase<<<NCH, 256, 0, stream>>>(abg, carry, W2, B2, out);
}